// Round 1
// baseline (196.424 us; speedup 1.0000x reference)
//
#include <hip/hip_runtime.h>

// Problem constants (reference: B=32, T=4096, E=256). B is hard-coded; T, E,
// maxlen are derived from in_sizes/out_size at launch.
#define NROWS 32

// ---------------------------------------------------------------------------
// Kernel 1: per-row scan of batch_x -> cut positions + segment counts.
// One block per row, 256 threads, each thread scans T/256 consecutive tokens.
// ---------------------------------------------------------------------------
__global__ void find_cuts_kernel(const int* __restrict__ batch_x, int T, int maxlen,
                                 int* __restrict__ cut_pos,      // [B, maxlen]
                                 int* __restrict__ n_cuts_i,     // [B]
                                 float* __restrict__ n_cuts_out) // [B], fp32 tail of d_out
{
    const int b = blockIdx.x;
    const int nt = blockDim.x;                 // 256
    const int per = (T + nt - 1) / nt;         // 16 for T=4096
    const int t0 = threadIdx.x * per;
    const int t1 = min(t0 + per, T);
    const int* row = batch_x + (long long)b * T;

    int local = 0;
    for (int t = t0; t < t1; ++t) local += (row[t] == 1);

    __shared__ int scan[256];
    scan[threadIdx.x] = local;
    __syncthreads();
    // inclusive scan (Hillis-Steele) over 256 per-thread counts
    for (int off = 1; off < nt; off <<= 1) {
        int v = (threadIdx.x >= off) ? scan[threadIdx.x - off] : 0;
        __syncthreads();
        scan[threadIdx.x] += v;
        __syncthreads();
    }
    int idx = scan[threadIdx.x] - local;       // exclusive prefix
    for (int t = t0; t < t1; ++t) {
        if (row[t] == 1) {
            cut_pos[b * maxlen + idx] = t;
            ++idx;
        }
    }
    if (threadIdx.x == nt - 1) {
        n_cuts_i[b] = scan[nt - 1];
        n_cuts_out[b] = (float)scan[nt - 1];
    }
}

// ---------------------------------------------------------------------------
// Kernel 2: mean-pool each segment. One wave (64 lanes) per (row, segment);
// lane l owns features [4l, 4l+4) as a float4 (requires E == 256). Fully
// coalesced: each token contributes one 1KB contiguous row per wave.
// ---------------------------------------------------------------------------
__global__ void pool_kernel(const float* __restrict__ nn,
                            const int* __restrict__ cut_pos,
                            const int* __restrict__ n_cuts_i,
                            int T, int E, int maxlen,
                            float* __restrict__ out)
{
    const int wave = (int)((blockIdx.x * (long long)blockDim.x + threadIdx.x) >> 6);
    const int lane = threadIdx.x & 63;
    const int total = NROWS * maxlen;
    if (wave >= total) return;
    const int b = wave / maxlen;
    const int k = wave - b * maxlen;

    const int nc = n_cuts_i[b];
    float4 acc = make_float4(0.f, 0.f, 0.f, 0.f);
    float inv = 0.f;
    if (k < nc) {
        const int start = (k == 0) ? 0 : (cut_pos[b * maxlen + k - 1] + 1);
        const int end   = cut_pos[b * maxlen + k];   // inclusive
        const int cnt   = end - start + 1;
        const float* base = nn + ((long long)b * T + start) * E + lane * 4;
        for (int t = 0; t < cnt; ++t) {
            const float4 v = *(const float4*)(base + (long long)t * E);
            acc.x += v.x; acc.y += v.y; acc.z += v.z; acc.w += v.w;
        }
        inv = 1.0f / (float)cnt;
    }
    acc.x *= inv; acc.y *= inv; acc.z *= inv; acc.w *= inv;
    float4* o = (float4*)(out + ((long long)b * maxlen + k) * E) + lane;
    *o = acc;
}

extern "C" void kernel_launch(void* const* d_in, const int* in_sizes, int n_in,
                              void* d_out, int out_size, void* d_ws, size_t ws_size,
                              hipStream_t stream) {
    const float* nn_outs = (const float*)d_in[0];
    const int*   batch_x = (const int*)d_in[1];
    float* out = (float*)d_out;

    const int B = NROWS;
    const long long bt = in_sizes[1];          // B*T
    const int T = (int)(bt / B);               // 4096
    const int E = (int)(in_sizes[0] / bt);     // 256
    const int maxlen = (out_size - B) / (B * E); // 256

    // workspace layout: cut_pos [B*maxlen] ints, n_cuts [B] ints
    int* cut_pos = (int*)d_ws;
    int* n_cuts_i = cut_pos + (size_t)B * maxlen;
    float* n_cuts_out = out + (size_t)B * maxlen * E;   // tail of d_out

    find_cuts_kernel<<<B, 256, 0, stream>>>(batch_x, T, maxlen,
                                            cut_pos, n_cuts_i, n_cuts_out);

    const int total_waves = B * maxlen;                 // one wave per segment
    const int waves_per_block = 4;                      // 256 threads
    const int blocks = (total_waves + waves_per_block - 1) / waves_per_block;
    pool_kernel<<<blocks, 256, 0, stream>>>(nn_outs, cut_pos, n_cuts_i,
                                            T, E, maxlen, out);
}